// Round 4
// baseline (243.711 us; speedup 1.0000x reference)
//
#include <hip/hip_runtime.h>
#include <hip/hip_bf16.h>

// SelfAttention: O = softmax(mask((X_q WQ)(X_k WK)^T/8)) (X_v WV), causal +
// key-padding (V_len) + query (Q_len) masks. B=8 S=1024 D=1024 H=16 Dh=64.
//
// All intermediates FP16 (11-bit mantissa, same MFMA rate as bf16). Values fit
// fp16 range: |q|<=0.5 (1/8 folded), |k|,|v|<=4, p=exp(s)<=~150 << 65504.
//
// Pipeline:
//   proj_gemm_all: ONE dispatch, 1536 blocks; slice 0/1 -> q_proj/k_proj
//                  [B][H][S][Dh], slice 2 -> vT [B][H][Dh][S] ((X WV)^T).
//   attn_fwd     : flash attention, shift-free softmax, vlen tile skipping,
//                  mask only on final tile, q-tile PAIRS {15-z, z} per block
//                  (constant 17 tiles/block -> no drain imbalance), explicit
//                  K double-buffer + early V loads (latency hiding).

#define B_  8
#define S_  1024
#define D_  1024
#define H_  16
#define DH_ 64

using f16x8  = __attribute__((ext_vector_type(8))) _Float16;
using s16x8  = __attribute__((ext_vector_type(8))) short;
using f32x4  = __attribute__((ext_vector_type(4))) float;
using s16x4  = __attribute__((ext_vector_type(4))) short;

__device__ inline short f2h(float x) {
  _Float16 h = (_Float16)x;  // RNE
  return __builtin_bit_cast(short, h);
}

__device__ inline f16x8 ld_frag_lds(const short* p) {  // p must be 8B aligned
  s16x4 a = *(const s16x4*)p;
  s16x4 b = *(const s16x4*)(p + 4);
  s16x8 r = {a[0], a[1], a[2], a[3], b[0], b[1], b[2], b[3]};
  return __builtin_bit_cast(f16x8, r);
}

__device__ inline f16x8 ld_frag_g(const short* p) {  // 16B aligned
  return __builtin_bit_cast(f16x8, *(const s16x8*)p);
}

// ---------------------------------------------------------------- projections
// One dispatch: 3 slices x 512 blocks. Tile 128x128, BK=32, 4 waves (2x2),
// each wave 64x64 = 4x4 mfma_f32_16x16x32_f16 fragments.
// mode 0: A = X (rows m0..), B = W (cols n0..), out = [B][H][S][Dh]
// mode 1: A = W^T (cols m0..), B = X^T (rows n0.. of X), out = [B][H][Dh][S]
#define LDP 44  // padded LDS row length (elements) -> 88B rows, 8B aligned

__global__ __launch_bounds__(256) void proj_gemm_all(
    const float* __restrict__ Qx, const float* __restrict__ Kx,
    const float* __restrict__ Vx, const float* __restrict__ WQ,
    const float* __restrict__ WK, const float* __restrict__ WV,
    short* __restrict__ qp, short* __restrict__ kp, short* __restrict__ vp) {
  __shared__ short As[128][LDP];
  __shared__ short Bs[128][LDP];
  const int gid = blockIdx.x;
  const int slice = gid >> 9;
  const int r = gid & 511;

  const float* X;
  const float* W;
  short* out;
  float oscale;
  int mode;
  if (slice == 0) {
    X = Qx; W = WQ; out = qp; oscale = 0.125f; mode = 0;
  } else if (slice == 1) {
    X = Kx; W = WK; out = kp; oscale = 1.0f; mode = 0;
  } else {
    X = Vx; W = WV; out = vp; oscale = 1.0f; mode = 1;
  }
  const int m0 = (mode == 0 ? (r >> 3) : (r & 7)) * 128;
  const int n0 = (mode == 0 ? (r & 7) : (r >> 3)) * 128;

  const int tid = threadIdx.x;
  const int lane = tid & 63;
  const int w = tid >> 6;
  const int wr = w >> 1, wc = w & 1;
  const int lr = lane & 15, lg = lane >> 4;

  f32x4 acc[4][4];
#pragma unroll
  for (int i = 0; i < 4; ++i)
#pragma unroll
    for (int j = 0; j < 4; ++j) acc[i][j] = f32x4{0.f, 0.f, 0.f, 0.f};

  for (int kt = 0; kt < D_ / 32; ++kt) {
    const int k0 = kt * 32;
    if (mode == 0) {
      {  // A direct from X
        const int rr = tid >> 3, f = tid & 7;
#pragma unroll
        for (int i = 0; i < 4; ++i) {
          const int row = rr + i * 32;
          float4 v = *(const float4*)(X + (size_t)(m0 + row) * D_ + k0 + f * 4);
          s16x4 sv = {f2h(v.x), f2h(v.y), f2h(v.z), f2h(v.w)};
          *(s16x4*)(&As[row][f * 4]) = sv;
        }
      }
      {  // B transposed from W (Bs[n][k] = W[k][n0+n])
        const int c = tid & 31, kq = tid >> 5;
#pragma unroll
        for (int i = 0; i < 4; ++i) {
          const int col = c + i * 32;
          const float* gp = W + (size_t)(k0 + kq * 4) * D_ + n0 + col;
          s16x4 sv = {f2h(gp[0]), f2h(gp[D_]), f2h(gp[2 * D_]),
                      f2h(gp[3 * D_])};
          *(s16x4*)(&Bs[col][kq * 4]) = sv;
        }
      }
    } else {
      {  // A transposed from W (As[r][k] = W[k][m0+r])
        const int c = tid & 31, kq = tid >> 5;
#pragma unroll
        for (int i = 0; i < 4; ++i) {
          const int col = c + i * 32;
          const float* gp = W + (size_t)(k0 + kq * 4) * D_ + m0 + col;
          s16x4 sv = {f2h(gp[0]), f2h(gp[D_]), f2h(gp[2 * D_]),
                      f2h(gp[3 * D_])};
          *(s16x4*)(&As[col][kq * 4]) = sv;
        }
      }
      {  // B direct from X rows n0..
        const int rr = tid >> 3, f = tid & 7;
#pragma unroll
        for (int i = 0; i < 4; ++i) {
          const int row = rr + i * 32;
          float4 v = *(const float4*)(X + (size_t)(n0 + row) * D_ + k0 + f * 4);
          s16x4 sv = {f2h(v.x), f2h(v.y), f2h(v.z), f2h(v.w)};
          *(s16x4*)(&Bs[row][f * 4]) = sv;
        }
      }
    }
    __syncthreads();

    f16x8 af[4], bfr[4];
#pragma unroll
    for (int mi = 0; mi < 4; ++mi)
      af[mi] = ld_frag_lds(&As[wr * 64 + mi * 16 + lr][lg * 8]);
#pragma unroll
    for (int ni = 0; ni < 4; ++ni)
      bfr[ni] = ld_frag_lds(&Bs[wc * 64 + ni * 16 + lr][lg * 8]);
#pragma unroll
    for (int mi = 0; mi < 4; ++mi)
#pragma unroll
      for (int ni = 0; ni < 4; ++ni)
        acc[mi][ni] = __builtin_amdgcn_mfma_f32_16x16x32_f16(
            af[mi], bfr[ni], acc[mi][ni], 0, 0, 0);
    __syncthreads();
  }

#pragma unroll
  for (int mi = 0; mi < 4; ++mi)
#pragma unroll
    for (int ni = 0; ni < 4; ++ni) {
      const int mgb = m0 + wr * 64 + mi * 16 + lg * 4;
      const int ng = n0 + wc * 64 + ni * 16 + lr;
#pragma unroll
      for (int reg = 0; reg < 4; ++reg) {
        const int m = mgb + reg;
        const short val = f2h(acc[mi][ni][reg] * oscale);
        if (mode == 0) {
          const int b = m >> 10, s = m & 1023, hh = ng >> 6, dh = ng & 63;
          out[((size_t)((b * H_ + hh) * S_) + s) * DH_ + dh] = val;
        } else {
          const int hh = m >> 6, dh = m & 63, b = ng >> 10, s = ng & 1023;
          out[((size_t)((b * H_ + hh) * DH_) + dh) * S_ + s] = val;
        }
      }
    }
}

// ----------------------------------------------------------------- attention
// Block = (b, h, z): processes q-tiles {15-z, z} (constant total causal work).
// 4 waves x 16 q rows. KV tiles of 64. Shift-free softmax (p = exp(s), scores
// tiny; exp(s - 1e12) == 0.0f exactly, matching the reference's mask collapse).
// Tiles with kv0 >= vlen skipped (contribute exactly 0 when vlen>0); vlen==0
// degrades to plain causal softmax. Mask predication only on the final tile.
// K fragments double-buffered in registers; V fragments loaded before the
// QK^T/softmax of the same tile (latency hidden under compute).
__global__ __launch_bounds__(256, 3) void attn_fwd(
    const short* __restrict__ qp, const short* __restrict__ kp,
    const short* __restrict__ vT, const int* __restrict__ Qlen,
    const int* __restrict__ Vlen, float* __restrict__ out) {
  __shared__ short Plds[4][16][72];  // per-wave private P tile
  const int bid = blockIdx.x;
  const int z = bid & 7;
  const int bh = bid >> 3;
  const int h = bh & 15;
  const int b = bh >> 4;
  const int lane = threadIdx.x & 63;
  const int w = threadIdx.x >> 6;
  const int lr = lane & 15, lg = lane >> 4;
  const short* qb = qp + (size_t)((b * H_ + h) * S_) * DH_;
  const short* kb = kp + (size_t)((b * H_ + h) * S_) * DH_;
  const short* vb = vT + (size_t)((b * H_ + h) * DH_) * S_;
  const int vlen = Vlen[b], qlen = Qlen[b];

  for (int half = 0; half < 2; ++half) {
    const int qt = half ? z : 15 - z;  // heavy tile first
    const int q0 = qt * 64 + w * 16;
    const int nT = (vlen > 0) ? min(qt + 1, (vlen + 63) >> 6) : (qt + 1);

    f16x8 qf[2];
#pragma unroll
    for (int c = 0; c < 2; ++c)
      qf[c] = ld_frag_g(qb + (size_t)(q0 + lr) * DH_ + c * 32 + lg * 8);

    float l[4];
    f32x4 o[4];
#pragma unroll
    for (int rr = 0; rr < 4; ++rr) {
      l[rr] = 0.f;
      o[rr] = f32x4{0.f, 0.f, 0.f, 0.f};
    }

    f16x8 kf[8];  // current K tile fragments [nt*2+c]
#pragma unroll
    for (int nt = 0; nt < 4; ++nt)
#pragma unroll
      for (int c = 0; c < 2; ++c)
        kf[nt * 2 + c] =
            ld_frag_g(kb + (size_t)(nt * 16 + lr) * DH_ + c * 32 + lg * 8);

    for (int t = 0; t < nT; ++t) {
      const int kv0 = t * 64;
      const int kvn = (t + 1 < nT) ? kv0 + 64 : kv0;  // clamped prefetch

      f16x8 vf[8];  // V for THIS tile — issued before QK/softmax
#pragma unroll
      for (int dt = 0; dt < 4; ++dt)
#pragma unroll
        for (int c = 0; c < 2; ++c)
          vf[dt * 2 + c] = ld_frag_g(vb + (size_t)(dt * 16 + lr) * S_ + kv0 +
                                     c * 32 + lg * 8);

      f16x8 kn[8];  // K for NEXT tile
#pragma unroll
      for (int nt = 0; nt < 4; ++nt)
#pragma unroll
        for (int c = 0; c < 2; ++c)
          kn[nt * 2 + c] = ld_frag_g(kb + (size_t)(kvn + nt * 16 + lr) * DH_ +
                                     c * 32 + lg * 8);

      f32x4 s[4];
#pragma unroll
      for (int nt = 0; nt < 4; ++nt) s[nt] = f32x4{0.f, 0.f, 0.f, 0.f};
#pragma unroll
      for (int nt = 0; nt < 4; ++nt)
#pragma unroll
        for (int c = 0; c < 2; ++c)
          s[nt] = __builtin_amdgcn_mfma_f32_16x16x32_f16(qf[c], kf[nt * 2 + c],
                                                         s[nt], 0, 0, 0);

      const bool km = (vlen > 0) && (vlen - kv0 < 64);  // key-mask here
      if ((t == qt) | km) {  // only possible on the last tile
#pragma unroll
        for (int reg = 0; reg < 4; ++reg) {
          const int qrow = q0 + lg * 4 + reg;
#pragma unroll
          for (int nt = 0; nt < 4; ++nt) {
            const int kv = kv0 + nt * 16 + lr;
            float sv = s[nt][reg];
            if (km && kv >= vlen) sv -= 1e12f;  // key padding -> exp == 0
            if (kv > qrow) sv -= 1e12f;         // causal -> exp == 0
            const float p = __expf(sv);
            l[reg] += p;
            Plds[w][lg * 4 + reg][nt * 16 + lr] = f2h(p);
          }
        }
      } else {  // interior tile: mask-free
#pragma unroll
        for (int reg = 0; reg < 4; ++reg)
#pragma unroll
          for (int nt = 0; nt < 4; ++nt) {
            const float p = __expf(s[nt][reg]);
            l[reg] += p;
            Plds[w][lg * 4 + reg][nt * 16 + lr] = f2h(p);
          }
      }

#pragma unroll
      for (int c = 0; c < 2; ++c) {
        f16x8 pa = ld_frag_lds(&Plds[w][lr][c * 32 + lg * 8]);
#pragma unroll
        for (int dt = 0; dt < 4; ++dt)
          o[dt] = __builtin_amdgcn_mfma_f32_16x16x32_f16(pa, vf[dt * 2 + c],
                                                         o[dt], 0, 0, 0);
      }

#pragma unroll
      for (int i = 0; i < 8; ++i) kf[i] = kn[i];
    }

#pragma unroll
    for (int reg = 0; reg < 4; ++reg) {
      float ls = l[reg];
      ls += __shfl_xor(ls, 1);
      ls += __shfl_xor(ls, 2);
      ls += __shfl_xor(ls, 4);
      ls += __shfl_xor(ls, 8);
      const int qrow = q0 + lg * 4 + reg;
      const float sc = (qrow < qlen) ? (1.f / ls) : 0.f;
#pragma unroll
      for (int dt = 0; dt < 4; ++dt)
        out[(size_t)(b * S_ + qrow) * D_ + h * DH_ + dt * 16 + lr] =
            o[dt][reg] * sc;
    }
  }
}

// ------------------------------------------------------------------- launch
extern "C" void kernel_launch(void* const* d_in, const int* in_sizes, int n_in,
                              void* d_out, int out_size, void* d_ws,
                              size_t ws_size, hipStream_t stream) {
  const float* Q = (const float*)d_in[0];
  const float* K = (const float*)d_in[1];
  const float* V = (const float*)d_in[2];
  const float* WQ = (const float*)d_in[3];
  const float* WK = (const float*)d_in[4];
  const float* WV = (const float*)d_in[5];
  const int* Qlen = (const int*)d_in[6];
  const int* Vlen = (const int*)d_in[7];
  float* out = (float*)d_out;

  const size_t PE = (size_t)B_ * H_ * S_ * DH_;  // 8388608 elements
  short* qp = (short*)d_ws;
  short* kp = qp + PE;
  short* vT = kp + PE;  // total 48 MiB of d_ws

  dim3 blk(256);
  proj_gemm_all<<<dim3(1536), blk, 0, stream>>>(Q, K, V, WQ, WK, WV, qp, kp,
                                                vT);
  attn_fwd<<<dim3(1024), blk, 0, stream>>>(qp, kp, vT, Qlen, Vlen, out);
}

// Round 5
// 168.562 us; speedup vs baseline: 1.4458x; 1.4458x over previous
//
#include <hip/hip_runtime.h>
#include <hip/hip_bf16.h>

// SelfAttention: O = softmax(mask((X_q WQ)(X_k WK)^T/8)) (X_v WV), causal +
// key-padding (V_len) + query (Q_len) masks. B=8 S=1024 D=1024 H=16 Dh=64.
//
// All intermediates FP16 (11-bit mantissa, same MFMA rate as bf16). Values fit
// fp16 range: |q|<=0.5 (1/8 folded), |k|,|v|<=4, p=exp(s)<=~150 << 65504.
//
// Pipeline:
//   proj_gemm_all: ONE dispatch, 1536 blocks; slice 0/1 -> q_proj/k_proj
//                  [B][H][S][Dh], slice 2 -> vT [B][H][Dh][S] ((X WV)^T).
//                  Block order m-fast/n-slow within slice => co-resident
//                  blocks share one W slab (L2-resident, no thrash).
//   attn_fwd     : flash attention, shift-free softmax, vlen tile skipping,
//                  masks only on final tiles. Block = (b,h,z) handles q-tiles
//                  {15-z, z} in ONE fused KV sweep: shared tiles loaded once,
//                  feeding QK^T+PV for both halves (2x MFMA per byte).

#define B_  8
#define S_  1024
#define D_  1024
#define H_  16
#define DH_ 64

using f16x8  = __attribute__((ext_vector_type(8))) _Float16;
using s16x8  = __attribute__((ext_vector_type(8))) short;
using f32x4  = __attribute__((ext_vector_type(4))) float;
using s16x4  = __attribute__((ext_vector_type(4))) short;

__device__ inline short f2h(float x) {
  _Float16 h = (_Float16)x;  // RNE
  return __builtin_bit_cast(short, h);
}

__device__ inline f16x8 ld_frag_lds(const short* p) {  // p must be 8B aligned
  s16x4 a = *(const s16x4*)p;
  s16x4 b = *(const s16x4*)(p + 4);
  s16x8 r = {a[0], a[1], a[2], a[3], b[0], b[1], b[2], b[3]};
  return __builtin_bit_cast(f16x8, r);
}

__device__ inline f16x8 ld_frag_g(const short* p) {  // 16B aligned
  return __builtin_bit_cast(f16x8, *(const s16x8*)p);
}

// ---------------------------------------------------------------- projections
// One dispatch: 3 slices x 512 blocks. Tile 128x128, BK=32, 4 waves (2x2),
// each wave 64x64 = 4x4 mfma_f32_16x16x32_f16 fragments.
// mode 0: A = X (rows m0..), B = W (cols n0..), out = [B][H][S][Dh]
//         m-index fast (r&63): 64 consecutive blocks share one 512KB W slab.
// mode 1: A = W^T (cols m0..), B = X^T (rows n0..), out = [B][H][Dh][S]
//         m-index fast (r&7): 8 consecutive blocks share one X row-band.
#define LDP 44  // padded LDS row length (elements) -> 88B rows, 8B aligned

__global__ __launch_bounds__(256) void proj_gemm_all(
    const float* __restrict__ Qx, const float* __restrict__ Kx,
    const float* __restrict__ Vx, const float* __restrict__ WQ,
    const float* __restrict__ WK, const float* __restrict__ WV,
    short* __restrict__ qp, short* __restrict__ kp, short* __restrict__ vp) {
  __shared__ short As[128][LDP];
  __shared__ short Bs[128][LDP];
  const int gid = blockIdx.x;
  const int slice = gid >> 9;
  const int r = gid & 511;

  const float* X;
  const float* W;
  short* out;
  float oscale;
  int mode;
  if (slice == 0) {
    X = Qx; W = WQ; out = qp; oscale = 0.125f; mode = 0;
  } else if (slice == 1) {
    X = Kx; W = WK; out = kp; oscale = 1.0f; mode = 0;
  } else {
    X = Vx; W = WV; out = vp; oscale = 1.0f; mode = 1;
  }
  const int m0 = (mode == 0 ? (r & 63) : (r & 7)) * 128;
  const int n0 = (mode == 0 ? (r >> 6) : (r >> 3)) * 128;

  const int tid = threadIdx.x;
  const int lane = tid & 63;
  const int w = tid >> 6;
  const int wr = w >> 1, wc = w & 1;
  const int lr = lane & 15, lg = lane >> 4;

  f32x4 acc[4][4];
#pragma unroll
  for (int i = 0; i < 4; ++i)
#pragma unroll
    for (int j = 0; j < 4; ++j) acc[i][j] = f32x4{0.f, 0.f, 0.f, 0.f};

  for (int kt = 0; kt < D_ / 32; ++kt) {
    const int k0 = kt * 32;
    if (mode == 0) {
      {  // A direct from X
        const int rr = tid >> 3, f = tid & 7;
#pragma unroll
        for (int i = 0; i < 4; ++i) {
          const int row = rr + i * 32;
          float4 v = *(const float4*)(X + (size_t)(m0 + row) * D_ + k0 + f * 4);
          s16x4 sv = {f2h(v.x), f2h(v.y), f2h(v.z), f2h(v.w)};
          *(s16x4*)(&As[row][f * 4]) = sv;
        }
      }
      {  // B transposed from W (Bs[n][k] = W[k][n0+n])
        const int c = tid & 31, kq = tid >> 5;
#pragma unroll
        for (int i = 0; i < 4; ++i) {
          const int col = c + i * 32;
          const float* gp = W + (size_t)(k0 + kq * 4) * D_ + n0 + col;
          s16x4 sv = {f2h(gp[0]), f2h(gp[D_]), f2h(gp[2 * D_]),
                      f2h(gp[3 * D_])};
          *(s16x4*)(&Bs[col][kq * 4]) = sv;
        }
      }
    } else {
      {  // A transposed from W (As[r][k] = W[k][m0+r])
        const int c = tid & 31, kq = tid >> 5;
#pragma unroll
        for (int i = 0; i < 4; ++i) {
          const int col = c + i * 32;
          const float* gp = W + (size_t)(k0 + kq * 4) * D_ + m0 + col;
          s16x4 sv = {f2h(gp[0]), f2h(gp[D_]), f2h(gp[2 * D_]),
                      f2h(gp[3 * D_])};
          *(s16x4*)(&As[col][kq * 4]) = sv;
        }
      }
      {  // B direct from X rows n0..
        const int rr = tid >> 3, f = tid & 7;
#pragma unroll
        for (int i = 0; i < 4; ++i) {
          const int row = rr + i * 32;
          float4 v = *(const float4*)(X + (size_t)(n0 + row) * D_ + k0 + f * 4);
          s16x4 sv = {f2h(v.x), f2h(v.y), f2h(v.z), f2h(v.w)};
          *(s16x4*)(&Bs[row][f * 4]) = sv;
        }
      }
    }
    __syncthreads();

    f16x8 af[4], bfr[4];
#pragma unroll
    for (int mi = 0; mi < 4; ++mi)
      af[mi] = ld_frag_lds(&As[wr * 64 + mi * 16 + lr][lg * 8]);
#pragma unroll
    for (int ni = 0; ni < 4; ++ni)
      bfr[ni] = ld_frag_lds(&Bs[wc * 64 + ni * 16 + lr][lg * 8]);
#pragma unroll
    for (int mi = 0; mi < 4; ++mi)
#pragma unroll
      for (int ni = 0; ni < 4; ++ni)
        acc[mi][ni] = __builtin_amdgcn_mfma_f32_16x16x32_f16(
            af[mi], bfr[ni], acc[mi][ni], 0, 0, 0);
    __syncthreads();
  }

#pragma unroll
  for (int mi = 0; mi < 4; ++mi)
#pragma unroll
    for (int ni = 0; ni < 4; ++ni) {
      const int mgb = m0 + wr * 64 + mi * 16 + lg * 4;
      const int ng = n0 + wc * 64 + ni * 16 + lr;
#pragma unroll
      for (int reg = 0; reg < 4; ++reg) {
        const int m = mgb + reg;
        const short val = f2h(acc[mi][ni][reg] * oscale);
        if (mode == 0) {
          const int b = m >> 10, s = m & 1023, hh = ng >> 6, dh = ng & 63;
          out[((size_t)((b * H_ + hh) * S_) + s) * DH_ + dh] = val;
        } else {
          const int hh = m >> 6, dh = m & 63, b = ng >> 10, s = ng & 1023;
          out[((size_t)((b * H_ + hh) * DH_) + dh) * S_ + s] = val;
        }
      }
    }
}

// ----------------------------------------------------------------- attention
// Block = (b, h, z): q-tiles {qtH=15-z, qtL=z}, ONE fused sweep over KV tiles
// t = 0..nTH-1; the light half participates while t < nTL, so shared tiles
// are loaded once and feed both halves' QK^T and PV MFMAs.
// Shift-free softmax (p = exp(s); exp(s - 1e12) == 0.0f exactly). Tiles with
// kv0 >= vlen skipped (vlen>0); vlen==0 degrades to plain causal softmax.
// Mask predication only where needed (own causal tile / vlen boundary tile).
__global__ __launch_bounds__(256, 2) void attn_fwd(
    const short* __restrict__ qp, const short* __restrict__ kp,
    const short* __restrict__ vT, const int* __restrict__ Qlen,
    const int* __restrict__ Vlen, float* __restrict__ out) {
  __shared__ short Plds[2][4][16][72];  // [half][wave] private P tiles
  const int bid = blockIdx.x;
  const int z = bid & 7;
  const int bh = bid >> 3;
  const int h = bh & 15;
  const int b = bh >> 4;
  const int lane = threadIdx.x & 63;
  const int w = threadIdx.x >> 6;
  const int lr = lane & 15, lg = lane >> 4;
  const short* qb = qp + (size_t)((b * H_ + h) * S_) * DH_;
  const short* kb = kp + (size_t)((b * H_ + h) * S_) * DH_;
  const short* vb = vT + (size_t)((b * H_ + h) * DH_) * S_;
  const int vlen = Vlen[b], qlen = Qlen[b];

  const int qtH = 15 - z, qtL = z;
  const int vcap = (vlen + 63) >> 6;
  const int nTH = (vlen > 0) ? min(qtH + 1, vcap) : (qtH + 1);
  const int nTL = (vlen > 0) ? min(qtL + 1, vcap) : (qtL + 1);
  const int q0H = qtH * 64 + w * 16;
  const int q0L = qtL * 64 + w * 16;

  f16x8 qfH[2], qfL[2];
#pragma unroll
  for (int c = 0; c < 2; ++c) {
    qfH[c] = ld_frag_g(qb + (size_t)(q0H + lr) * DH_ + c * 32 + lg * 8);
    qfL[c] = ld_frag_g(qb + (size_t)(q0L + lr) * DH_ + c * 32 + lg * 8);
  }

  float lH[4], lL[4];
  f32x4 oH[4], oL[4];
#pragma unroll
  for (int rr = 0; rr < 4; ++rr) {
    lH[rr] = 0.f; lL[rr] = 0.f;
    oH[rr] = f32x4{0.f, 0.f, 0.f, 0.f};
    oL[rr] = f32x4{0.f, 0.f, 0.f, 0.f};
  }

  f16x8 kf[8];  // current K tile fragments [nt*2+c]
#pragma unroll
  for (int nt = 0; nt < 4; ++nt)
#pragma unroll
    for (int c = 0; c < 2; ++c)
      kf[nt * 2 + c] =
          ld_frag_g(kb + (size_t)(nt * 16 + lr) * DH_ + c * 32 + lg * 8);

  for (int t = 0; t < nTH; ++t) {
    const int kv0 = t * 64;
    const int kvn = (t + 1 < nTH) ? kv0 + 64 : kv0;  // clamped prefetch
    const bool lact = t < nTL;

    f16x8 vf[8];  // V for THIS tile — issued before QK/softmax
#pragma unroll
    for (int dt = 0; dt < 4; ++dt)
#pragma unroll
      for (int c = 0; c < 2; ++c)
        vf[dt * 2 + c] =
            ld_frag_g(vb + (size_t)(dt * 16 + lr) * S_ + kv0 + c * 32 + lg * 8);

    f16x8 kn[8];  // K for NEXT tile
#pragma unroll
    for (int nt = 0; nt < 4; ++nt)
#pragma unroll
      for (int c = 0; c < 2; ++c)
        kn[nt * 2 + c] = ld_frag_g(kb + (size_t)(kvn + nt * 16 + lr) * DH_ +
                                   c * 32 + lg * 8);

    // ---- QK^T phase (both halves: up to 16 independent MFMAs)
    f32x4 sH[4], sL[4];
#pragma unroll
    for (int nt = 0; nt < 4; ++nt) sH[nt] = f32x4{0.f, 0.f, 0.f, 0.f};
#pragma unroll
    for (int nt = 0; nt < 4; ++nt)
#pragma unroll
      for (int c = 0; c < 2; ++c)
        sH[nt] = __builtin_amdgcn_mfma_f32_16x16x32_f16(qfH[c], kf[nt * 2 + c],
                                                        sH[nt], 0, 0, 0);
    if (lact) {
#pragma unroll
      for (int nt = 0; nt < 4; ++nt) sL[nt] = f32x4{0.f, 0.f, 0.f, 0.f};
#pragma unroll
      for (int nt = 0; nt < 4; ++nt)
#pragma unroll
        for (int c = 0; c < 2; ++c)
          sL[nt] = __builtin_amdgcn_mfma_f32_16x16x32_f16(
              qfL[c], kf[nt * 2 + c], sL[nt], 0, 0, 0);
    }

    const bool km = (vlen > 0) && (vlen - kv0 < 64);  // vlen boundary tile

    // ---- softmax phase (heavy)
    if ((t == qtH) | km) {
#pragma unroll
      for (int reg = 0; reg < 4; ++reg) {
        const int qrow = q0H + lg * 4 + reg;
#pragma unroll
        for (int nt = 0; nt < 4; ++nt) {
          const int kv = kv0 + nt * 16 + lr;
          float sv = sH[nt][reg];
          if (km && kv >= vlen) sv -= 1e12f;  // key padding -> exp == 0
          if (kv > qrow) sv -= 1e12f;         // causal -> exp == 0
          const float p = __expf(sv);
          lH[reg] += p;
          Plds[0][w][lg * 4 + reg][nt * 16 + lr] = f2h(p);
        }
      }
    } else {
#pragma unroll
      for (int reg = 0; reg < 4; ++reg)
#pragma unroll
        for (int nt = 0; nt < 4; ++nt) {
          const float p = __expf(sH[nt][reg]);
          lH[reg] += p;
          Plds[0][w][lg * 4 + reg][nt * 16 + lr] = f2h(p);
        }
    }
    // ---- softmax phase (light)
    if (lact) {
      if ((t == qtL) | km) {
#pragma unroll
        for (int reg = 0; reg < 4; ++reg) {
          const int qrow = q0L + lg * 4 + reg;
#pragma unroll
          for (int nt = 0; nt < 4; ++nt) {
            const int kv = kv0 + nt * 16 + lr;
            float sv = sL[nt][reg];
            if (km && kv >= vlen) sv -= 1e12f;
            if (kv > qrow) sv -= 1e12f;
            const float p = __expf(sv);
            lL[reg] += p;
            Plds[1][w][lg * 4 + reg][nt * 16 + lr] = f2h(p);
          }
        }
      } else {
#pragma unroll
        for (int reg = 0; reg < 4; ++reg)
#pragma unroll
          for (int nt = 0; nt < 4; ++nt) {
            const float p = __expf(sL[nt][reg]);
            lL[reg] += p;
            Plds[1][w][lg * 4 + reg][nt * 16 + lr] = f2h(p);
          }
      }
    }

    // ---- PV phase (both halves share vf)
#pragma unroll
    for (int c = 0; c < 2; ++c) {
      f16x8 paH = ld_frag_lds(&Plds[0][w][lr][c * 32 + lg * 8]);
#pragma unroll
      for (int dt = 0; dt < 4; ++dt)
        oH[dt] = __builtin_amdgcn_mfma_f32_16x16x32_f16(paH, vf[dt * 2 + c],
                                                        oH[dt], 0, 0, 0);
    }
    if (lact) {
#pragma unroll
      for (int c = 0; c < 2; ++c) {
        f16x8 paL = ld_frag_lds(&Plds[1][w][lr][c * 32 + lg * 8]);
#pragma unroll
        for (int dt = 0; dt < 4; ++dt)
          oL[dt] = __builtin_amdgcn_mfma_f32_16x16x32_f16(paL, vf[dt * 2 + c],
                                                          oL[dt], 0, 0, 0);
      }
    }

#pragma unroll
    for (int i = 0; i < 8; ++i) kf[i] = kn[i];
  }

  // ---- epilogue: both halves
#pragma unroll
  for (int reg = 0; reg < 4; ++reg) {
    float ls = lH[reg];
    ls += __shfl_xor(ls, 1);
    ls += __shfl_xor(ls, 2);
    ls += __shfl_xor(ls, 4);
    ls += __shfl_xor(ls, 8);
    const int qrow = q0H + lg * 4 + reg;
    const float sc = (qrow < qlen) ? (1.f / ls) : 0.f;
#pragma unroll
    for (int dt = 0; dt < 4; ++dt)
      out[(size_t)(b * S_ + qrow) * D_ + h * DH_ + dt * 16 + lr] =
          oH[dt][reg] * sc;
  }
#pragma unroll
  for (int reg = 0; reg < 4; ++reg) {
    float ls = lL[reg];
    ls += __shfl_xor(ls, 1);
    ls += __shfl_xor(ls, 2);
    ls += __shfl_xor(ls, 4);
    ls += __shfl_xor(ls, 8);
    const int qrow = q0L + lg * 4 + reg;
    const float sc = (qrow < qlen) ? (1.f / ls) : 0.f;
#pragma unroll
    for (int dt = 0; dt < 4; ++dt)
      out[(size_t)(b * S_ + qrow) * D_ + h * DH_ + dt * 16 + lr] =
          oL[dt][reg] * sc;
  }
}

// ------------------------------------------------------------------- launch
extern "C" void kernel_launch(void* const* d_in, const int* in_sizes, int n_in,
                              void* d_out, int out_size, void* d_ws,
                              size_t ws_size, hipStream_t stream) {
  const float* Q = (const float*)d_in[0];
  const float* K = (const float*)d_in[1];
  const float* V = (const float*)d_in[2];
  const float* WQ = (const float*)d_in[3];
  const float* WK = (const float*)d_in[4];
  const float* WV = (const float*)d_in[5];
  const int* Qlen = (const int*)d_in[6];
  const int* Vlen = (const int*)d_in[7];
  float* out = (float*)d_out;

  const size_t PE = (size_t)B_ * H_ * S_ * DH_;  // 8388608 elements
  short* qp = (short*)d_ws;
  short* kp = qp + PE;
  short* vT = kp + PE;  // total 48 MiB of d_ws

  dim3 blk(256);
  proj_gemm_all<<<dim3(1536), blk, 0, stream>>>(Q, K, V, WQ, WK, WV, qp, kp,
                                                vT);
  attn_fwd<<<dim3(1024), blk, 0, stream>>>(qp, kp, vT, Qlen, Vlen, out);
}